// Round 13
// baseline (216.951 us; speedup 1.0000x reference)
//
#include <hip/hip_runtime.h>
#include <hip/hip_bf16.h>

#define N_NODES 50000
#define N_EDGES 800000
#define EP (N_EDGES + N_NODES)   // with self-loops
#define IN_C 128
#define HID 64
#define HEADS 2
#define LAT 32
#define NEG_SLOPE 0.2f
#define MAXDEG 256     // max in-degree; Poisson(17) -> P(>200) ~ 0
#define NBUCKET 391    // ceil(N_NODES/128): coarse dst-buckets of 128 nodes
#define BCAP 3072      // bucket capacity; expect ~2176 +- 47 (20 sigma margin)
#define CHUNK 2048     // edges per scatter block (18KB LDS -> 8 blocks/CU)
#define NSCAT ((EP + CHUNK - 1) / CHUNK)   // 416 scatter blocks
#define NPROJ1 ((N_NODES + 31) / 32)       // 1563 proj1 blocks

typedef __attribute__((ext_vector_type(8))) short bf16x8;
typedef __attribute__((ext_vector_type(4))) float f32x4;

// fp32 -> bf16 round-to-nearest-even
__device__ __forceinline__ unsigned short f2bf(float f) {
  unsigned u = __float_as_uint(f);
  u += 0x7FFF + ((u >> 16) & 1);
  return (unsigned short)(u >> 16);
}
__device__ __forceinline__ float bf_lo(unsigned u) { return __uint_as_float(u << 16); }
__device__ __forceinline__ float bf_hi(unsigned u) { return __uint_as_float(u & 0xFFFF0000u); }

__device__ __forceinline__ bf16x8 pack_bf8(const float* __restrict__ p) {
  float4 a = *(const float4*)p;
  float4 b = *(const float4*)(p + 4);
  bf16x8 r;
  r[0] = (short)f2bf(a.x); r[1] = (short)f2bf(a.y);
  r[2] = (short)f2bf(a.z); r[3] = (short)f2bf(a.w);
  r[4] = (short)f2bf(b.x); r[5] = (short)f2bf(b.y);
  r[6] = (short)f2bf(b.z); r[7] = (short)f2bf(b.w);
  return r;
}

// ======= prep: zero cursors + pack W1/[Wmu|Wlv] into B-fragment layout ======
// Wb layout: [(kk*4+quad)*N + n]*8 + j  holds  W[k = kk*32+quad*8+j][n]
__global__ __launch_bounds__(256) void prep_kernel(
    const float* __restrict__ W1, const float* __restrict__ Wmu,
    const float* __restrict__ Wlv, int* __restrict__ cursor,
    unsigned short* __restrict__ Wb1g, unsigned short* __restrict__ Wb2g) {
  const int b = blockIdx.x, t = threadIdx.x;
  if (b == 0) {
    for (int i = t; i < NBUCKET; i += 256) cursor[i] = 0;
  } else if (b <= 64) {
    int i = (b - 1) * 256 + t;       // [0, 16384)
    int k = i >> 7, n = i & 127;
    int kk = k >> 5, q = (k >> 3) & 3, j = k & 7;
    Wb1g[((((kk << 2) + q) << 7) + n) * 8 + j] = f2bf(W1[i]);
  } else {
    int i = (b - 65) * 256 + t;      // [0, 8192)
    int k = i >> 6, n = i & 63;
    float v = (n < 32) ? Wmu[k * 32 + n] : Wlv[k * 32 + (n - 32)];
    int kk = k >> 5, q = (k >> 3) & 3, j = k & 7;
    Wb2g[((((kk << 2) + q) << 6) + n) * 8 + j] = f2bf(v);
  }
}

// ---------------- K1 shared-memory overlay (scatter | proj1) ----------------
struct ScatSmem {
  int histL[512];
  int baseL[512];
  int gbaseL[512];
  int wsumS[4];
  int nvalS;
  unsigned staging[CHUNK];
  unsigned short bktidL[CHUNK];
};
union K1Smem { ScatSmem sc; float part[32][4]; };

// ================= K1: bucket_scatter (blocks 0..NSCAT) =====================
// =================     proj1 (MFMA, global B-frags) + fused a1 ==============
__global__ __launch_bounds__(256) void k1_kernel(
    const int* __restrict__ ei, int* __restrict__ cursor,
    unsigned* __restrict__ csr,
    const float* __restrict__ x, const unsigned short* __restrict__ Wb1g,
    const float* __restrict__ att_src, const float* __restrict__ att_dst,
    unsigned short* __restrict__ h1b, float* __restrict__ a1) {
  __shared__ K1Smem sm;
  const int t = threadIdx.x, lane = t & 63, wid = t >> 6;

  if (blockIdx.x < NSCAT) {
    // ---------------- bucket scatter: LDS binning, chunked global writes ----
    for (int i = t; i < 512; i += 256) sm.sc.histL[i] = 0;
    __syncthreads();
    int myb[CHUNK / 256];
    int myloc[CHUNK / 256];
    unsigned mypay[CHUNK / 256];
    #pragma unroll
    for (int i = 0; i < CHUNK / 256; ++i) {
      int e = blockIdx.x * CHUNK + i * 256 + t;
      if (e < EP) {
        int s, d;
        if (e < N_EDGES) { s = ei[e]; d = ei[N_EDGES + e]; }
        else { s = d = e - N_EDGES; }
        int b = d >> 7;
        myb[i] = b;
        mypay[i] = ((unsigned)(d & 127) << 17) | (unsigned)s;  // s < 2^17
        myloc[i] = atomicAdd(&sm.sc.histL[b], 1);
      } else myb[i] = -1;
    }
    __syncthreads();
    {   // exclusive scan of histL[0..511]
      int v0 = sm.sc.histL[2 * t], v1 = sm.sc.histL[2 * t + 1];
      int pair = v0 + v1, inc = pair;
      #pragma unroll
      for (int off = 1; off < 64; off <<= 1) {
        int nv = __shfl_up(inc, off);
        if (lane >= off) inc += nv;
      }
      if (lane == 63) sm.sc.wsumS[wid] = inc;
      __syncthreads();
      if (t == 0) {
        int run = 0;
        #pragma unroll
        for (int w = 0; w < 4; ++w) { int c = sm.sc.wsumS[w]; sm.sc.wsumS[w] = run; run += c; }
        sm.sc.nvalS = run;
      }
      __syncthreads();
      int excl = sm.sc.wsumS[wid] + inc - pair;
      sm.sc.baseL[2 * t] = excl;
      sm.sc.baseL[2 * t + 1] = excl + v0;
    }
    __syncthreads();
    #pragma unroll
    for (int i = 0; i < CHUNK / 256; ++i)
      if (myb[i] >= 0) {
        int p = sm.sc.baseL[myb[i]] + myloc[i];
        sm.sc.staging[p] = mypay[i];
        sm.sc.bktidL[p] = (unsigned short)myb[i];
      }
    for (int b = t; b < NBUCKET; b += 256) {   // reserve chunks (relative)
      int c = sm.sc.histL[b];
      sm.sc.gbaseL[b] = c ? atomicAdd(&cursor[b], c) : 0;
    }
    __syncthreads();
    const int nval = sm.sc.nvalS;
    for (int j = t; j < nval; j += 256) {
      int b = sm.sc.bktidL[j];
      int off = sm.sc.gbaseL[b] + (j - sm.sc.baseL[b]);
      if (off < BCAP) csr[b * BCAP + off] = sm.sc.staging[j];  // overflow guard
    }
  } else {
    // ---------------- proj1 (MFMA) + fused a1 epilogue ----------------------
    const int pb = blockIdx.x - NSCAT;        // 0..NPROJ1-1
    if (t < 128) ((float*)sm.part)[t] = 0.f;
    __syncthreads();
    const int w = wid;
    const int m = lane & 15, quad = lane >> 4;
    const int row0 = pb * 32;
    const int n0 = w * 32;
    const int head = w >> 1;                  // cols n0.. all in one head
    f32x4 acc[2][2] = {};
    #pragma unroll
    for (int kk = 0; kk < 4; ++kk) {
      bf16x8 afr[2], bfr[2];
      #pragma unroll
      for (int mt = 0; mt < 2; ++mt) {
        int row = row0 + mt * 16 + m;
        if (row >= N_NODES) row = N_NODES - 1;
        afr[mt] = pack_bf8(x + (size_t)row * 128 + kk * 32 + quad * 8);
      }
      #pragma unroll
      for (int nt = 0; nt < 2; ++nt)
        bfr[nt] = *(const bf16x8*)&Wb1g[((((kk << 2) + quad) << 7) + n0 + nt * 16 + m) * 8];
      #pragma unroll
      for (int mt = 0; mt < 2; ++mt)
        #pragma unroll
        for (int nt = 0; nt < 2; ++nt)
          acc[mt][nt] = __builtin_amdgcn_mfma_f32_16x16x32_bf16(
              afr[mt], bfr[nt], acc[mt][nt], 0, 0, 0);
    }
    // per-lane att values for this wave's two 16-col groups (within head)
    float asv[2], adv[2];
    #pragma unroll
    for (int nt = 0; nt < 2; ++nt) {
      int cc = ((n0 & 63) + nt * 16 + m);
      asv[nt] = att_src[head * HID + cc];
      adv[nt] = att_dst[head * HID + cc];
    }
    #pragma unroll
    for (int mt = 0; mt < 2; ++mt)
      #pragma unroll
      for (int r = 0; r < 4; ++r) {
        int row = row0 + mt * 16 + quad * 4 + r;
        if (row < N_NODES) {
          #pragma unroll
          for (int nt = 0; nt < 2; ++nt)
            h1b[(size_t)row * 128 + n0 + nt * 16 + m] = f2bf(acc[mt][nt][r]);
        }
        float s = acc[mt][0][r] * asv[0] + acc[mt][1][r] * asv[1];
        float d = acc[mt][0][r] * adv[0] + acc[mt][1][r] * adv[1];
        #pragma unroll
        for (int off = 8; off; off >>= 1) {   // reduce 16 col-lanes (in-quad)
          s += __shfl_xor(s, off);
          d += __shfl_xor(d, off);
        }
        if (m == 0) {   // two waves per head accumulate
          atomicAdd(&sm.part[mt * 16 + quad * 4 + r][head], s);
          atomicAdd(&sm.part[mt * 16 + quad * 4 + r][2 + head], d);
        }
      }
    __syncthreads();
    if (t < 32) {
      int row = row0 + t;
      if (row < N_NODES)
        *(float4*)&a1[(size_t)row * 4] = make_float4(
            sm.part[t][0], sm.part[t][1], sm.part[t][2], sm.part[t][3]);
    }
  }
}

// Phase 2: one block per bucket; per-node histogram + prefix + in-place
// re-scatter within an L2-local 12 KB window.
__global__ __launch_bounds__(256) void bucket_fill_kernel(
    const int* __restrict__ cursor, unsigned* __restrict__ csr,
    int* __restrict__ counts, int* __restrict__ cend) {
  __shared__ unsigned eseg[BCAP];
  __shared__ int hist[128];
  __shared__ int basef[128];
  __shared__ int cur[128];
  const int b = blockIdx.x, t = threadIdx.x;
  const int segbase = b * BCAP;
  int cnt = cursor[b];
  if (cnt > BCAP) cnt = BCAP;
  if (t < 128) hist[t] = 0;
  __syncthreads();
  for (int j = t; j < cnt; j += 256) {
    unsigned u = csr[segbase + j];
    eseg[j] = u;
    atomicAdd(&hist[u >> 17], 1);
  }
  __syncthreads();
  if (t < 64) {   // exclusive scan of hist[0..127]
    int v0 = hist[2 * t], v1 = hist[2 * t + 1];
    int pair = v0 + v1, inc = pair;
    #pragma unroll
    for (int off = 1; off < 64; off <<= 1) {
      int nv = __shfl_up(inc, off);
      if (t >= off) inc += nv;
    }
    int excl = inc - pair;
    basef[2 * t] = excl;
    basef[2 * t + 1] = excl + v0;
  }
  __syncthreads();
  if (t < 128) {
    cur[t] = basef[t];
    int n = b * 128 + t;
    if (n < N_NODES) {
      counts[n] = hist[t];
      cend[n] = segbase + basef[t] + hist[t];
    }
  }
  __syncthreads();
  for (int j = t; j < cnt; j += 256) {
    unsigned u = eseg[j];
    int dl = u >> 17;
    int p = atomicAdd(&cur[dl], 1);
    csr[segbase + p] = u & 0x1FFFF;    // src id only
  }
}

// ---- layer-1 gather-aggregate: per-head (byte_off, w) LDS records; phase B
// is one ds_read_b64 broadcast + one 4-B gather + 2 FMA per edge.
// hact stays fp32 (R11 lesson: quantizing layer-2's GEMM input costs ~1.5e-2
// absmax — over threshold). -------------------------------------------------
__global__ __launch_bounds__(64) void agg1_csr_kernel(
    const int* __restrict__ counts, const int* __restrict__ cend,
    const unsigned* __restrict__ csr_src, const float4* __restrict__ a1,
    const unsigned* __restrict__ h1b2, const float* __restrict__ b,
    float* __restrict__ hact) {
  __shared__ int ewA[MAXDEG][2];   // (s*256, bits(w_head0))
  __shared__ int ewB[MAXDEG][2];   // (s*256, bits(w_head1))
  const int n = blockIdx.x;
  const int t = threadIdx.x;
  const int end = cend[n];
  int cnt = counts[n];
  if (cnt > MAXDEG) cnt = MAXDEG;
  const int beg = end - cnt;
  const float4 bv = a1[n];
  float p0 = 0.f, p1 = 0.f;
  for (int i = t; i < cnt; i += 64) {
    int s = (int)csr_src[beg + i];
    float4 av = a1[s];
    float l0 = av.x + bv.z; l0 = l0 > 0.f ? l0 : NEG_SLOPE * l0;
    float l1 = av.y + bv.w; l1 = l1 > 0.f ? l1 : NEG_SLOPE * l1;
    float e0 = expf(l0), e1 = expf(l1);
    int soff = s << 8;               // byte offset of h1b row (128 ch * 2 B)
    ewA[i][0] = soff; ewA[i][1] = __float_as_int(e0);
    ewB[i][0] = soff; ewB[i][1] = __float_as_int(e1);
    p0 += e0; p1 += e1;
  }
  #pragma unroll
  for (int off = 32; off; off >>= 1) {
    p0 += __shfl_xor(p0, off);
    p1 += __shfl_xor(p1, off);
  }
  __syncthreads();
  const int head = t >> 5;
  const int (*ew)[2] = head ? ewB : ewA;
  const char* hbase = (const char*)h1b2 + t * 4;   // lane channel-pair offset
  float ax = 0.f, ay = 0.f;
  #pragma unroll 4
  for (int i = 0; i < cnt; ++i) {
    int soff = ew[i][0];
    float w = __int_as_float(ew[i][1]);
    unsigned u = *(const unsigned*)(hbase + soff);
    ax += bf_lo(u) * w; ay += bf_hi(u) * w;
  }
  float inv = 1.f / ((head ? p1 : p0) + 1e-16f);
  float vx = ax * inv + b[t * 2];
  float vy = ay * inv + b[t * 2 + 1];
  vx = vx > 0.f ? vx : (expf(vx) - 1.f);
  vy = vy > 0.f ? vy : (expf(vy) - 1.f);
  *(float2*)(hact + (size_t)n * 128 + t * 2) = make_float2(vx, vy);
}

// ------- proj2 (MFMA, global B-frags, fp32 hact A-frags) + fused a2 ---------
__global__ __launch_bounds__(256) void proj2_kernel(
    const float* __restrict__ h,
    const unsigned short* __restrict__ Wb2g,
    const float* __restrict__ asmu, const float* __restrict__ admu,
    const float* __restrict__ aslv, const float* __restrict__ adlv,
    unsigned short* __restrict__ h2b, float* __restrict__ a2) {
  const int t = threadIdx.x;
  const int w = t >> 6, lane = t & 63;
  const int m = lane & 15, quad = lane >> 4;
  const int row0 = blockIdx.x * 64 + (w >> 1) * 32;
  const int j = w & 1;                 // 0 = mu, 1 = lv
  const int n0 = j * 32;
  f32x4 acc[2][2] = {};
  #pragma unroll
  for (int kk = 0; kk < 4; ++kk) {
    bf16x8 afr[2], bfr[2];
    #pragma unroll
    for (int mt = 0; mt < 2; ++mt) {
      int row = row0 + mt * 16 + m;
      if (row >= N_NODES) row = N_NODES - 1;
      afr[mt] = pack_bf8(h + (size_t)row * 128 + kk * 32 + quad * 8);
    }
    #pragma unroll
    for (int nt = 0; nt < 2; ++nt)
      bfr[nt] = *(const bf16x8*)&Wb2g[((((kk << 2) + quad) << 6) + n0 + nt * 16 + m) * 8];
    #pragma unroll
    for (int mt = 0; mt < 2; ++mt)
      #pragma unroll
      for (int nt = 0; nt < 2; ++nt)
        acc[mt][nt] = __builtin_amdgcn_mfma_f32_16x16x32_bf16(
            afr[mt], bfr[nt], acc[mt][nt], 0, 0, 0);
  }
  float asv[2], adv[2];
  #pragma unroll
  for (int nt = 0; nt < 2; ++nt) {
    int o = nt * 16 + m;
    asv[nt] = (j ? aslv : asmu)[o];
    adv[nt] = (j ? adlv : admu)[o];
  }
  #pragma unroll
  for (int mt = 0; mt < 2; ++mt)
    #pragma unroll
    for (int r = 0; r < 4; ++r) {
      int row = row0 + mt * 16 + quad * 4 + r;
      if (row < N_NODES) {
        #pragma unroll
        for (int nt = 0; nt < 2; ++nt)
          h2b[(size_t)row * 64 + n0 + nt * 16 + m] = f2bf(acc[mt][nt][r]);
      }
      float s = acc[mt][0][r] * asv[0] + acc[mt][1][r] * asv[1];
      float d = acc[mt][0][r] * adv[0] + acc[mt][1][r] * adv[1];
      #pragma unroll
      for (int off = 8; off; off >>= 1) {   // reduce 16 col-lanes
        s += __shfl_xor(s, off);
        d += __shfl_xor(d, off);
      }
      if (m == 0 && row < N_NODES) {
        a2[(size_t)row * 4 + j * 2 + 0] = s;   // (s_mu, d_mu, s_lv, d_lv)
        a2[(size_t)row * 4 + j * 2 + 1] = d;
      }
    }
}

// ---- layer-2 gather-aggregate: 2 nodes/block, per-j (byte_off, w) records --
__global__ __launch_bounds__(64) void agg2_csr_kernel(
    const int* __restrict__ counts, const int* __restrict__ cend,
    const unsigned* __restrict__ csr_src, const float4* __restrict__ a2,
    const unsigned* __restrict__ h2b2,
    const float* __restrict__ bmu, const float* __restrict__ blv,
    float* __restrict__ out) {
  __shared__ int ewA[2][MAXDEG][2];   // per half: (s*128, bits(w_mu))
  __shared__ int ewB[2][MAXDEG][2];   // per half: (s*128, bits(w_lv))
  const int t = threadIdx.x, half = t >> 5, hl = t & 31;
  const int n = blockIdx.x * 2 + half;
  const int end = cend[n];
  int cnt = counts[n];
  if (cnt > MAXDEG) cnt = MAXDEG;
  const int beg = end - cnt;
  const float4 bv = a2[n];
  float p0 = 0.f, p1 = 0.f;
  for (int i = hl; i < cnt; i += 32) {
    int s = (int)csr_src[beg + i];
    float4 av = a2[s];
    float l0 = av.x + bv.y; l0 = l0 > 0.f ? l0 : NEG_SLOPE * l0;  // mu
    float l1 = av.z + bv.w; l1 = l1 > 0.f ? l1 : NEG_SLOPE * l1;  // lv
    float e0 = expf(l0), e1 = expf(l1);
    int soff = s << 7;               // byte offset of h2b row (64 ch * 2 B)
    ewA[half][i][0] = soff; ewA[half][i][1] = __float_as_int(e0);
    ewB[half][i][0] = soff; ewB[half][i][1] = __float_as_int(e1);
    p0 += e0; p1 += e1;
  }
  #pragma unroll
  for (int off = 16; off; off >>= 1) {   // butterfly within 32-lane half
    p0 += __shfl_xor(p0, off);
    p1 += __shfl_xor(p1, off);
  }
  __syncthreads();
  const int c0 = 2 * hl;             // channels (c0, c0+1) of the h2 row
  const int j = c0 >> 5;             // 0 = mu, 1 = lv
  const int o = c0 & 31;
  const int (*ew)[2] = (j ? ewB : ewA)[half];
  const char* hbase = (const char*)h2b2 + hl * 4;
  float ax = 0.f, ay = 0.f;
  #pragma unroll 4
  for (int i = 0; i < cnt; ++i) {
    int soff = ew[i][0];
    float w = __int_as_float(ew[i][1]);
    unsigned u = *(const unsigned*)(hbase + soff);
    ax += bf_lo(u) * w; ay += bf_hi(u) * w;
  }
  float inv = 1.f / ((j ? p1 : p0) + 1e-16f);
  const float* bb = j ? blv : bmu;
  *(float2*)&out[(size_t)j * N_NODES * LAT + (size_t)n * LAT + o] =
      make_float2(ax * inv + bb[o], ay * inv + bb[o + 1]);
}

extern "C" void kernel_launch(void* const* d_in, const int* in_sizes, int n_in,
                              void* d_out, int out_size, void* d_ws, size_t ws_size,
                              hipStream_t stream) {
  const float* x        = (const float*)d_in[0];
  const int* ei         = (const int*)d_in[1];   // int32 per harness contract
  const float* W1       = (const float*)d_in[2];
  const float* att_src1 = (const float*)d_in[3];
  const float* att_dst1 = (const float*)d_in[4];
  const float* b1       = (const float*)d_in[5];
  const float* Wmu      = (const float*)d_in[6];
  const float* asmu     = (const float*)d_in[7];
  const float* admu     = (const float*)d_in[8];
  const float* bmu      = (const float*)d_in[9];
  const float* Wlv      = (const float*)d_in[10];
  const float* aslv     = (const float*)d_in[11];
  const float* adlv     = (const float*)d_in[12];
  const float* blv      = (const float*)d_in[13];
  float* out = (float*)d_out;

  // workspace layout (4-B word units), all 16-B-loaded buffers 16-B aligned:
  //  hact fp32 @0 (N*128 w) | a1 @N*128 (N*4) | a2 @N*132 (N*4) |
  //  h1b bf16 @N*136 (N*64 w) | h2b bf16 @N*200 (N*32 w) | Wb1g @N*232 (8192 w)
  //  | Wb2g (4096 w) | counts | cend | cursor | csr
  float* ws   = (float*)d_ws;
  float* hact = ws;
  float* a1   = ws + (size_t)N_NODES * 128;
  float* a2   = a1 + (size_t)N_NODES * 4;
  unsigned short* h1b = (unsigned short*)(a2 + (size_t)N_NODES * 4);
  unsigned short* h2b = h1b + (size_t)N_NODES * 128;
  unsigned short* Wb1g = h2b + (size_t)N_NODES * 64;       // 16-B aligned
  unsigned short* Wb2g = Wb1g + 16384;                     // 16-B aligned
  int* counts = (int*)(Wb2g + 8192);
  int* cend   = counts + N_NODES;
  int* cursor = cend + N_NODES;
  unsigned* csr = (unsigned*)(cursor + NBUCKET);

  // prep: zero cursors + pack both weight matrices into B-frag layout
  prep_kernel<<<97, 256, 0, stream>>>(W1, Wmu, Wlv, cursor, Wb1g, Wb2g);

  // K1: bucket_scatter (416 blocks) || proj1+a1 (1563 blocks)
  k1_kernel<<<NSCAT + NPROJ1, 256, 0, stream>>>(
      ei, cursor, csr, x, Wb1g, att_src1, att_dst1, h1b, a1);
  bucket_fill_kernel<<<NBUCKET, 256, 0, stream>>>(cursor, csr, counts, cend);
  agg1_csr_kernel<<<N_NODES, 64, 0, stream>>>(
      counts, cend, csr, (const float4*)a1, (const unsigned*)h1b, b1, hact);
  proj2_kernel<<<(N_NODES + 63) / 64, 256, 0, stream>>>(
      hact, Wb2g, asmu, admu, aslv, adlv, h2b, a2);
  agg2_csr_kernel<<<N_NODES / 2, 64, 0, stream>>>(
      counts, cend, csr, (const float4*)a2, (const unsigned*)h2b, bmu, blv, out);
}

// Round 14
// 209.875 us; speedup vs baseline: 1.0337x; 1.0337x over previous
//
#include <hip/hip_runtime.h>
#include <hip/hip_bf16.h>

#define N_NODES 50000
#define N_EDGES 800000
#define EP (N_EDGES + N_NODES)   // with self-loops
#define IN_C 128
#define HID 64
#define HEADS 2
#define LAT 32
#define NEG_SLOPE 0.2f
#define MAXDEG 256     // max in-degree; Poisson(17) -> P(>200) ~ 0
#define NBUCKET 391    // ceil(N_NODES/128): coarse dst-buckets of 128 nodes
#define BCAP 3072      // bucket capacity; expect ~2176 +- 47 (20 sigma margin)
#define CHUNK 2048     // edges per scatter block (18KB LDS -> 8 blocks/CU)
#define NSCAT ((EP + CHUNK - 1) / CHUNK)   // 416 scatter blocks
#define NPROJ1 ((N_NODES + 31) / 32)       // 1563 proj1 blocks

typedef __attribute__((ext_vector_type(8))) short bf16x8;
typedef __attribute__((ext_vector_type(4))) float f32x4;

// fp32 -> bf16 round-to-nearest-even
__device__ __forceinline__ unsigned short f2bf(float f) {
  unsigned u = __float_as_uint(f);
  u += 0x7FFF + ((u >> 16) & 1);
  return (unsigned short)(u >> 16);
}
__device__ __forceinline__ float bf_lo(unsigned u) { return __uint_as_float(u << 16); }
__device__ __forceinline__ float bf_hi(unsigned u) { return __uint_as_float(u & 0xFFFF0000u); }

__device__ __forceinline__ bf16x8 pack_bf8(const float* __restrict__ p) {
  float4 a = *(const float4*)p;
  float4 b = *(const float4*)(p + 4);
  bf16x8 r;
  r[0] = (short)f2bf(a.x); r[1] = (short)f2bf(a.y);
  r[2] = (short)f2bf(a.z); r[3] = (short)f2bf(a.w);
  r[4] = (short)f2bf(b.x); r[5] = (short)f2bf(b.y);
  r[6] = (short)f2bf(b.z); r[7] = (short)f2bf(b.w);
  return r;
}

// ======= prep: zero cursors + pack W1/[Wmu|Wlv] into B-fragment layout ======
// Wb layout: [(kk*4+quad)*N + n]*8 + j  holds  W[k = kk*32+quad*8+j][n]
__global__ __launch_bounds__(256) void prep_kernel(
    const float* __restrict__ W1, const float* __restrict__ Wmu,
    const float* __restrict__ Wlv, int* __restrict__ cursor,
    unsigned short* __restrict__ Wb1g, unsigned short* __restrict__ Wb2g) {
  const int b = blockIdx.x, t = threadIdx.x;
  if (b == 0) {
    for (int i = t; i < NBUCKET; i += 256) cursor[i] = 0;
  } else if (b <= 64) {
    int i = (b - 1) * 256 + t;       // [0, 16384)
    int k = i >> 7, n = i & 127;
    int kk = k >> 5, q = (k >> 3) & 3, j = k & 7;
    Wb1g[((((kk << 2) + q) << 7) + n) * 8 + j] = f2bf(W1[i]);
  } else {
    int i = (b - 65) * 256 + t;      // [0, 8192)
    int k = i >> 6, n = i & 63;
    float v = (n < 32) ? Wmu[k * 32 + n] : Wlv[k * 32 + (n - 32)];
    int kk = k >> 5, q = (k >> 3) & 3, j = k & 7;
    Wb2g[((((kk << 2) + q) << 6) + n) * 8 + j] = f2bf(v);
  }
}

// ---------------- K1 shared-memory overlay (scatter | proj1) ----------------
struct ScatSmem {
  int histL[512];
  int baseL[512];
  int gbaseL[512];
  int wsumS[4];
  int nvalS;
  unsigned staging[CHUNK];
  unsigned short bktidL[CHUNK];
};
union K1Smem { ScatSmem sc; float part[32][4]; };

// ================= K1: bucket_scatter (blocks 0..NSCAT) =====================
// =================     proj1 (MFMA, global B-frags) + fused a1 ==============
__global__ __launch_bounds__(256) void k1_kernel(
    const int* __restrict__ ei, int* __restrict__ cursor,
    unsigned* __restrict__ csr,
    const float* __restrict__ x, const unsigned short* __restrict__ Wb1g,
    const float* __restrict__ att_src, const float* __restrict__ att_dst,
    unsigned short* __restrict__ h1b, float* __restrict__ a1) {
  __shared__ K1Smem sm;
  const int t = threadIdx.x, lane = t & 63, wid = t >> 6;

  if (blockIdx.x < NSCAT) {
    // ---------------- bucket scatter: LDS binning, chunked global writes ----
    for (int i = t; i < 512; i += 256) sm.sc.histL[i] = 0;
    __syncthreads();
    int myb[CHUNK / 256];
    int myloc[CHUNK / 256];
    unsigned mypay[CHUNK / 256];
    #pragma unroll
    for (int i = 0; i < CHUNK / 256; ++i) {
      int e = blockIdx.x * CHUNK + i * 256 + t;
      if (e < EP) {
        int s, d;
        if (e < N_EDGES) { s = ei[e]; d = ei[N_EDGES + e]; }
        else { s = d = e - N_EDGES; }
        int b = d >> 7;
        myb[i] = b;
        mypay[i] = ((unsigned)(d & 127) << 17) | (unsigned)s;  // s < 2^17
        myloc[i] = atomicAdd(&sm.sc.histL[b], 1);
      } else myb[i] = -1;
    }
    __syncthreads();
    {   // exclusive scan of histL[0..511]
      int v0 = sm.sc.histL[2 * t], v1 = sm.sc.histL[2 * t + 1];
      int pair = v0 + v1, inc = pair;
      #pragma unroll
      for (int off = 1; off < 64; off <<= 1) {
        int nv = __shfl_up(inc, off);
        if (lane >= off) inc += nv;
      }
      if (lane == 63) sm.sc.wsumS[wid] = inc;
      __syncthreads();
      if (t == 0) {
        int run = 0;
        #pragma unroll
        for (int w = 0; w < 4; ++w) { int c = sm.sc.wsumS[w]; sm.sc.wsumS[w] = run; run += c; }
        sm.sc.nvalS = run;
      }
      __syncthreads();
      int excl = sm.sc.wsumS[wid] + inc - pair;
      sm.sc.baseL[2 * t] = excl;
      sm.sc.baseL[2 * t + 1] = excl + v0;
    }
    __syncthreads();
    #pragma unroll
    for (int i = 0; i < CHUNK / 256; ++i)
      if (myb[i] >= 0) {
        int p = sm.sc.baseL[myb[i]] + myloc[i];
        sm.sc.staging[p] = mypay[i];
        sm.sc.bktidL[p] = (unsigned short)myb[i];
      }
    for (int b = t; b < NBUCKET; b += 256) {   // reserve chunks (relative)
      int c = sm.sc.histL[b];
      sm.sc.gbaseL[b] = c ? atomicAdd(&cursor[b], c) : 0;
    }
    __syncthreads();
    const int nval = sm.sc.nvalS;
    for (int j = t; j < nval; j += 256) {
      int b = sm.sc.bktidL[j];
      int off = sm.sc.gbaseL[b] + (j - sm.sc.baseL[b]);
      if (off < BCAP) csr[b * BCAP + off] = sm.sc.staging[j];  // overflow guard
    }
  } else {
    // ---------------- proj1 (MFMA) + fused a1 epilogue ----------------------
    const int pb = blockIdx.x - NSCAT;        // 0..NPROJ1-1
    if (t < 128) ((float*)sm.part)[t] = 0.f;
    __syncthreads();
    const int w = wid;
    const int m = lane & 15, quad = lane >> 4;
    const int row0 = pb * 32;
    const int n0 = w * 32;
    const int head = w >> 1;                  // cols n0.. all in one head
    f32x4 acc[2][2] = {};
    #pragma unroll
    for (int kk = 0; kk < 4; ++kk) {
      bf16x8 afr[2], bfr[2];
      #pragma unroll
      for (int mt = 0; mt < 2; ++mt) {
        int row = row0 + mt * 16 + m;
        if (row >= N_NODES) row = N_NODES - 1;
        afr[mt] = pack_bf8(x + (size_t)row * 128 + kk * 32 + quad * 8);
      }
      #pragma unroll
      for (int nt = 0; nt < 2; ++nt)
        bfr[nt] = *(const bf16x8*)&Wb1g[((((kk << 2) + quad) << 7) + n0 + nt * 16 + m) * 8];
      #pragma unroll
      for (int mt = 0; mt < 2; ++mt)
        #pragma unroll
        for (int nt = 0; nt < 2; ++nt)
          acc[mt][nt] = __builtin_amdgcn_mfma_f32_16x16x32_bf16(
              afr[mt], bfr[nt], acc[mt][nt], 0, 0, 0);
    }
    // per-lane att values for this wave's two 16-col groups (within head)
    float asv[2], adv[2];
    #pragma unroll
    for (int nt = 0; nt < 2; ++nt) {
      int cc = ((n0 & 63) + nt * 16 + m);
      asv[nt] = att_src[head * HID + cc];
      adv[nt] = att_dst[head * HID + cc];
    }
    #pragma unroll
    for (int mt = 0; mt < 2; ++mt)
      #pragma unroll
      for (int r = 0; r < 4; ++r) {
        int row = row0 + mt * 16 + quad * 4 + r;
        if (row < N_NODES) {
          #pragma unroll
          for (int nt = 0; nt < 2; ++nt)
            h1b[(size_t)row * 128 + n0 + nt * 16 + m] = f2bf(acc[mt][nt][r]);
        }
        float s = acc[mt][0][r] * asv[0] + acc[mt][1][r] * asv[1];
        float d = acc[mt][0][r] * adv[0] + acc[mt][1][r] * adv[1];
        #pragma unroll
        for (int off = 8; off; off >>= 1) {   // reduce 16 col-lanes (in-quad)
          s += __shfl_xor(s, off);
          d += __shfl_xor(d, off);
        }
        if (m == 0) {   // two waves per head accumulate
          atomicAdd(&sm.part[mt * 16 + quad * 4 + r][head], s);
          atomicAdd(&sm.part[mt * 16 + quad * 4 + r][2 + head], d);
        }
      }
    __syncthreads();
    if (t < 32) {
      int row = row0 + t;
      if (row < N_NODES)
        *(float4*)&a1[(size_t)row * 4] = make_float4(
            sm.part[t][0], sm.part[t][1], sm.part[t][2], sm.part[t][3]);
    }
  }
}

// Phase 2: one block per bucket; per-node histogram + prefix + in-place
// re-scatter within an L2-local 12 KB window.
__global__ __launch_bounds__(256) void bucket_fill_kernel(
    const int* __restrict__ cursor, unsigned* __restrict__ csr,
    int* __restrict__ counts, int* __restrict__ cend) {
  __shared__ unsigned eseg[BCAP];
  __shared__ int hist[128];
  __shared__ int basef[128];
  __shared__ int cur[128];
  const int b = blockIdx.x, t = threadIdx.x;
  const int segbase = b * BCAP;
  int cnt = cursor[b];
  if (cnt > BCAP) cnt = BCAP;
  if (t < 128) hist[t] = 0;
  __syncthreads();
  for (int j = t; j < cnt; j += 256) {
    unsigned u = csr[segbase + j];
    eseg[j] = u;
    atomicAdd(&hist[u >> 17], 1);
  }
  __syncthreads();
  if (t < 64) {   // exclusive scan of hist[0..127]
    int v0 = hist[2 * t], v1 = hist[2 * t + 1];
    int pair = v0 + v1, inc = pair;
    #pragma unroll
    for (int off = 1; off < 64; off <<= 1) {
      int nv = __shfl_up(inc, off);
      if (t >= off) inc += nv;
    }
    int excl = inc - pair;
    basef[2 * t] = excl;
    basef[2 * t + 1] = excl + v0;
  }
  __syncthreads();
  if (t < 128) {
    cur[t] = basef[t];
    int n = b * 128 + t;
    if (n < N_NODES) {
      counts[n] = hist[t];
      cend[n] = segbase + basef[t] + hist[t];
    }
  }
  __syncthreads();
  for (int j = t; j < cnt; j += 256) {
    unsigned u = eseg[j];
    int dl = u >> 17;
    int p = atomicAdd(&cur[dl], 1);
    csr[segbase + p] = u & 0x1FFFF;    // src id only
  }
}

// ---- layer-1 gather-aggregate: weights once per edge (LDS), bf16 gather ----
__global__ __launch_bounds__(64) void agg1_csr_kernel(
    const int* __restrict__ counts, const int* __restrict__ cend,
    const unsigned* __restrict__ csr_src, const float4* __restrict__ a1,
    const unsigned* __restrict__ h1b2, const float* __restrict__ b,
    float* __restrict__ hact) {
  __shared__ float w_lds[2][MAXDEG];
  __shared__ int   s_lds[MAXDEG];
  const int n = blockIdx.x;
  const int t = threadIdx.x;
  const int end = cend[n];
  int cnt = counts[n];
  if (cnt > MAXDEG) cnt = MAXDEG;
  const int beg = end - cnt;
  const float4 bv = a1[n];
  float p0 = 0.f, p1 = 0.f;
  for (int i = t; i < cnt; i += 64) {
    int s = (int)csr_src[beg + i];
    float4 av = a1[s];
    float l0 = av.x + bv.z; l0 = l0 > 0.f ? l0 : NEG_SLOPE * l0;
    float l1 = av.y + bv.w; l1 = l1 > 0.f ? l1 : NEG_SLOPE * l1;
    float e0 = expf(l0), e1 = expf(l1);
    w_lds[0][i] = e0; w_lds[1][i] = e1; s_lds[i] = s;
    p0 += e0; p1 += e1;
  }
  #pragma unroll
  for (int off = 32; off; off >>= 1) {
    p0 += __shfl_xor(p0, off);
    p1 += __shfl_xor(p1, off);
  }
  __syncthreads();
  const int head = t >> 5;
  const unsigned* hp = h1b2 + t;
  float ax = 0.f, ay = 0.f;
  #pragma unroll 4
  for (int i = 0; i < cnt; ++i) {
    int s = s_lds[i];
    float w = w_lds[head][i];
    unsigned u = hp[(size_t)s * 64];
    ax += bf_lo(u) * w; ay += bf_hi(u) * w;
  }
  float inv = 1.f / ((head ? p1 : p0) + 1e-16f);
  float vx = ax * inv + b[t * 2];
  float vy = ay * inv + b[t * 2 + 1];
  vx = vx > 0.f ? vx : (expf(vx) - 1.f);
  vy = vy > 0.f ? vy : (expf(vy) - 1.f);
  *(float2*)(hact + (size_t)n * 128 + t * 2) = make_float2(vx, vy);
}

// ------- proj2 (MFMA, global B-frags, fp32 hact A-frags) + fused a2 ---------
__global__ __launch_bounds__(256) void proj2_kernel(
    const float* __restrict__ h, const unsigned short* __restrict__ Wb2g,
    const float* __restrict__ asmu, const float* __restrict__ admu,
    const float* __restrict__ aslv, const float* __restrict__ adlv,
    unsigned short* __restrict__ h2b, float* __restrict__ a2) {
  const int t = threadIdx.x;
  const int w = t >> 6, lane = t & 63;
  const int m = lane & 15, quad = lane >> 4;
  const int row0 = blockIdx.x * 64 + (w >> 1) * 32;
  const int j = w & 1;                 // 0 = mu, 1 = lv
  const int n0 = j * 32;
  f32x4 acc[2][2] = {};
  #pragma unroll
  for (int kk = 0; kk < 4; ++kk) {
    bf16x8 afr[2], bfr[2];
    #pragma unroll
    for (int mt = 0; mt < 2; ++mt) {
      int row = row0 + mt * 16 + m;
      if (row >= N_NODES) row = N_NODES - 1;
      afr[mt] = pack_bf8(h + (size_t)row * 128 + kk * 32 + quad * 8);
    }
    #pragma unroll
    for (int nt = 0; nt < 2; ++nt)
      bfr[nt] = *(const bf16x8*)&Wb2g[((((kk << 2) + quad) << 6) + n0 + nt * 16 + m) * 8];
    #pragma unroll
    for (int mt = 0; mt < 2; ++mt)
      #pragma unroll
      for (int nt = 0; nt < 2; ++nt)
        acc[mt][nt] = __builtin_amdgcn_mfma_f32_16x16x32_bf16(
            afr[mt], bfr[nt], acc[mt][nt], 0, 0, 0);
  }
  float asv[2], adv[2];
  #pragma unroll
  for (int nt = 0; nt < 2; ++nt) {
    int o = nt * 16 + m;
    asv[nt] = (j ? aslv : asmu)[o];
    adv[nt] = (j ? adlv : admu)[o];
  }
  #pragma unroll
  for (int mt = 0; mt < 2; ++mt)
    #pragma unroll
    for (int r = 0; r < 4; ++r) {
      int row = row0 + mt * 16 + quad * 4 + r;
      if (row < N_NODES) {
        #pragma unroll
        for (int nt = 0; nt < 2; ++nt)
          h2b[(size_t)row * 64 + n0 + nt * 16 + m] = f2bf(acc[mt][nt][r]);
      }
      float s = acc[mt][0][r] * asv[0] + acc[mt][1][r] * asv[1];
      float d = acc[mt][0][r] * adv[0] + acc[mt][1][r] * adv[1];
      #pragma unroll
      for (int off = 8; off; off >>= 1) {   // reduce 16 col-lanes
        s += __shfl_xor(s, off);
        d += __shfl_xor(d, off);
      }
      if (m == 0 && row < N_NODES) {
        a2[(size_t)row * 4 + j * 2 + 0] = s;   // (s_mu, d_mu, s_lv, d_lv)
        a2[(size_t)row * 4 + j * 2 + 1] = d;
      }
    }
}

// ---- layer-2 gather-aggregate: 2 nodes/block, 32 lanes each, bf16 pairs ----
__global__ __launch_bounds__(64) void agg2_csr_kernel(
    const int* __restrict__ counts, const int* __restrict__ cend,
    const unsigned* __restrict__ csr_src, const float4* __restrict__ a2,
    const unsigned* __restrict__ h2b2,
    const float* __restrict__ bmu, const float* __restrict__ blv,
    float* __restrict__ out) {
  __shared__ float w_lds[2][2][MAXDEG];
  __shared__ int   s_lds[2][MAXDEG];
  const int t = threadIdx.x, half = t >> 5, hl = t & 31;
  const int n = blockIdx.x * 2 + half;
  const int end = cend[n];
  int cnt = counts[n];
  if (cnt > MAXDEG) cnt = MAXDEG;
  const int beg = end - cnt;
  const float4 bv = a2[n];
  float p0 = 0.f, p1 = 0.f;
  for (int i = hl; i < cnt; i += 32) {
    int s = (int)csr_src[beg + i];
    float4 av = a2[s];
    float l0 = av.x + bv.y; l0 = l0 > 0.f ? l0 : NEG_SLOPE * l0;  // mu
    float l1 = av.z + bv.w; l1 = l1 > 0.f ? l1 : NEG_SLOPE * l1;  // lv
    float e0 = expf(l0), e1 = expf(l1);
    w_lds[half][0][i] = e0; w_lds[half][1][i] = e1; s_lds[half][i] = s;
    p0 += e0; p1 += e1;
  }
  #pragma unroll
  for (int off = 16; off; off >>= 1) {   // butterfly within 32-lane half
    p0 += __shfl_xor(p0, off);
    p1 += __shfl_xor(p1, off);
  }
  __syncthreads();
  const int c0 = 2 * hl;             // channels (c0, c0+1) of the h2 row
  const int j = c0 >> 5;             // 0 = mu, 1 = lv
  const int o = c0 & 31;
  const unsigned* hp = h2b2 + hl;
  float ax = 0.f, ay = 0.f;
  #pragma unroll 4
  for (int i = 0; i < cnt; ++i) {
    int s = s_lds[half][i];
    float w = w_lds[half][j][i];
    unsigned u = hp[(size_t)s * 32];
    ax += bf_lo(u) * w; ay += bf_hi(u) * w;
  }
  float inv = 1.f / ((j ? p1 : p0) + 1e-16f);
  const float* bb = j ? blv : bmu;
  *(float2*)&out[(size_t)j * N_NODES * LAT + (size_t)n * LAT + o] =
      make_float2(ax * inv + bb[o], ay * inv + bb[o + 1]);
}

extern "C" void kernel_launch(void* const* d_in, const int* in_sizes, int n_in,
                              void* d_out, int out_size, void* d_ws, size_t ws_size,
                              hipStream_t stream) {
  const float* x        = (const float*)d_in[0];
  const int* ei         = (const int*)d_in[1];   // int32 per harness contract
  const float* W1       = (const float*)d_in[2];
  const float* att_src1 = (const float*)d_in[3];
  const float* att_dst1 = (const float*)d_in[4];
  const float* b1       = (const float*)d_in[5];
  const float* Wmu      = (const float*)d_in[6];
  const float* asmu     = (const float*)d_in[7];
  const float* admu     = (const float*)d_in[8];
  const float* bmu      = (const float*)d_in[9];
  const float* Wlv      = (const float*)d_in[10];
  const float* aslv     = (const float*)d_in[11];
  const float* adlv     = (const float*)d_in[12];
  const float* blv      = (const float*)d_in[13];
  float* out = (float*)d_out;

  // workspace layout (4-B units) — all 16-B-vector-loaded buffers 16-B aligned:
  //  [hact N*128 | a1 N*4 | a2 N*4 | h1b N*64 w (bf16 pairs) | h2b N*32 w |
  //   Wb1g 8192 w | Wb2g 4096 w | counts N | cend N | cursor NBUCKET | csr]
  float* ws   = (float*)d_ws;
  float* hact = ws;
  float* a1   = hact + (size_t)N_NODES * 128;
  float* a2   = a1 + (size_t)N_NODES * 4;
  unsigned short* h1b = (unsigned short*)(a2 + (size_t)N_NODES * 4);
  unsigned short* h2b = h1b + (size_t)N_NODES * 128;
  unsigned short* Wb1g = h2b + (size_t)N_NODES * 64;       // 16-B aligned
  unsigned short* Wb2g = Wb1g + 16384;                     // 16-B aligned
  int* counts = (int*)(Wb2g + 8192);
  int* cend   = counts + N_NODES;
  int* cursor = cend + N_NODES;
  unsigned* csr = (unsigned*)(cursor + NBUCKET);

  // prep: zero cursors + pack both weight matrices into B-frag layout
  prep_kernel<<<97, 256, 0, stream>>>(W1, Wmu, Wlv, cursor, Wb1g, Wb2g);

  // K1: bucket_scatter (416 blocks) || proj1+a1 (1563 blocks)
  k1_kernel<<<NSCAT + NPROJ1, 256, 0, stream>>>(
      ei, cursor, csr, x, Wb1g, att_src1, att_dst1, h1b, a1);
  bucket_fill_kernel<<<NBUCKET, 256, 0, stream>>>(cursor, csr, counts, cend);
  agg1_csr_kernel<<<N_NODES, 64, 0, stream>>>(
      counts, cend, csr, (const float4*)a1, (const unsigned*)h1b, b1, hact);
  proj2_kernel<<<(N_NODES + 63) / 64, 256, 0, stream>>>(
      hact, Wb2g, asmu, admu, aslv, adlv, h2b, a2);
  agg2_csr_kernel<<<N_NODES / 2, 64, 0, stream>>>(
      counts, cend, csr, (const float4*)a2, (const unsigned*)h2b, bmu, blv, out);
}